// Round 6
// baseline (609.406 us; speedup 1.0000x reference)
//
#include <hip/hip_runtime.h>
#include <hip/hip_cooperative_groups.h>
#include <math.h>

namespace cg = cooperative_groups;

#define NSPEC 7
#define NMOL 1024
#define APM 48
#define NATOMS (NMOL * APM)   // 49152
#define FDIM 384

typedef unsigned short u16;
typedef unsigned int u32;
typedef __attribute__((ext_vector_type(8))) short short8;
typedef __attribute__((ext_vector_type(4))) float floatx4;

// Packed-weight geometry: [s][ntile][kg][lane(64)][8] bf16, frag = 16B/lane.
#define W1_ELEMS_PER_S (16 * 12 * 64 * 8)   // 98304
#define W2_ELEMS_PER_S (12 * 8 * 64 * 8)    // 49152
#define W3_ELEMS_PER_S (10 * 6 * 64 * 8)    // 30720

// ws layout (bytes): g_cnt[8] @0, w1p @32, w2p, w3p, bucket u16[7*NATOMS]. ~3.2 MB.
#define WS_W1_OFF 32
#define WS_W2_OFF (WS_W1_OFF + 1376256)
#define WS_W3_OFF (WS_W2_OFF + 688128)
#define WS_BKT_OFF (WS_W3_OFF + 430080)

#define BUFST 264      // LDS activation row stride in u16 (16B-aligned)
#define GRID 512       // persistent cooperative grid: 2 blocks/CU (capacity is 4 -> safe)
#define BUCKET_BLOCKS 384
#define NTILE_TOTAL 266   // 112 W1 + 84 W2 + 70 W3 pack tiles

__device__ __forceinline__ float celu01(float x) {
    // celu(x,0.1): __expf = native v_exp (~6 VALU). Validated R4/R5: absmax 0.015625.
    float e = fmaf(0.1f, __expf(x * 10.0f), -0.1f);
    return x > 0.0f ? x : e;
}

__device__ __forceinline__ u16 bfr(float f) {  // fp32 -> bf16 RNE
    u32 u = __float_as_uint(f);
    u += 0x7fffu + ((u >> 16) & 1u);
    return (u16)(u >> 16);
}

__device__ __forceinline__ float bf2f(short s) {
    return __uint_as_float(((u32)(u16)s) << 16);
}

union U8 { short8 v; u16 u[8]; };

// ---- phase-1 pack: one (s,t2) 16-row weight tile, 128 threads, via LDS ----
template <int KGS, int NTILES>
__device__ __forceinline__ void pack_tile(const float* __restrict__ W,
                                          u16* __restrict__ dst,
                                          int s, int t2, u16* lds) {
    const int K = KGS * 32;
    const int K4 = K / 4;                  // compile-time -> cheap div
    int t = threadIdx.x;
    const float* wbase = W + (size_t)(s * NTILES + t2) * 16 * K;
    for (int i = t; i < 16 * K4; i += 128) {
        int r = i / K4, c = i - r * K4;
        float4 v = ((const float4*)(wbase + (size_t)r * K))[c];
        u16* d = lds + r * K + c * 4;
        d[0] = bfr(v.x); d[1] = bfr(v.y); d[2] = bfr(v.z); d[3] = bfr(v.w);
    }
    __syncthreads();
    int w = t >> 6, lane = t & 63;
    int n = lane & 15, ks = lane >> 4;
    for (int kg = w; kg < KGS; kg += 2) {
        short8 v = *reinterpret_cast<const short8*>(lds + n * K + kg * 32 + ks * 8);
        *reinterpret_cast<short8*>(
            dst + (((size_t)(s * NTILES + t2) * KGS + kg) * 64 + lane) * 8) = v;
    }
    __syncthreads();   // LDS reused by next tile / phase 2
}

// ---- MFMA layer: 32 atoms/wave, NBUF-deep register-rotated B (R5-proven) ----
template <int KGS, int NT, int NBUF>
__device__ __forceinline__ void run_layer(const short8* af0, const short8* af1,
                                          const u16* wsp, const float* bias,
                                          u16* outbuf, int lane) {
    const int nl = lane & 15, kg4 = lane >> 4;
    const u16* wb = wsp + (size_t)lane * 8;
    short8 b[NBUF][KGS];
#pragma unroll
    for (int p = 0; p < NBUF - 1; ++p)
#pragma unroll
        for (int kg = 0; kg < KGS; ++kg)
            b[p][kg] = *reinterpret_cast<const short8*>(wb + ((size_t)p * KGS + kg) * 512);
#pragma unroll
    for (int t = 0; t < NT; ++t) {
        int pre = t + NBUF - 1;
        if (pre < NT) {
            int slot = pre % NBUF;
#pragma unroll
            for (int kg = 0; kg < KGS; ++kg)
                b[slot][kg] = *reinterpret_cast<const short8*>(wb + ((size_t)pre * KGS + kg) * 512);
        }
        int cur = t % NBUF;
        floatx4 acc0 = {0.f, 0.f, 0.f, 0.f};
        floatx4 acc1 = {0.f, 0.f, 0.f, 0.f};
#pragma unroll
        for (int kg = 0; kg < KGS; ++kg) {
            acc0 = __builtin_amdgcn_mfma_f32_16x16x32_bf16(af0[kg], b[cur][kg], acc0, 0, 0, 0);
            acc1 = __builtin_amdgcn_mfma_f32_16x16x32_bf16(af1[kg], b[cur][kg], acc1, 0, 0, 0);
        }
        float bn = bias[t * 16 + nl];
#pragma unroll
        for (int r = 0; r < 4; ++r) {
            outbuf[(kg4 * 4 + r) * BUFST + t * 16 + nl] = bfr(celu01(acc0[r] + bn));
            outbuf[(16 + kg4 * 4 + r) * BUFST + t * 16 + nl] = bfr(celu01(acc1[r] + bn));
        }
    }
}

template <int KGS>
__device__ __forceinline__ void load_a_lds(const u16* buf, short8* af0, short8* af1, int lane) {
    int nl = lane & 15, kg4 = lane >> 4;
#pragma unroll
    for (int kg = 0; kg < KGS; ++kg) {
        af0[kg] = *reinterpret_cast<const short8*>(buf + (size_t)nl * BUFST + kg * 32 + kg4 * 8);
        af1[kg] = *reinterpret_cast<const short8*>(buf + (size_t)(16 + nl) * BUFST + kg * 32 + kg4 * 8);
    }
}

// ---- the single fused cooperative kernel ----
__global__ __launch_bounds__(128, 2) void fused_kernel(
    const int* species, const float* aev,
    const float* W1, const float* W2, const float* W3,
    const float* b1, const float* b2, const float* b3,
    const float* W4, const float* b4,
    int* g_cnt, u16* bucket,
    u16* w1p, u16* w2p, u16* w3p,
    float* out) {
    // Shared scratch: phase-1 pack uses first 12.3 KB; phase-2 wave-private
    // activation buffers use all 33792 B. Histogram arrays coexist.
    __shared__ __align__(16) u16 smem[2 * 32 * BUFST];
    __shared__ int l_cnt[NSPEC];
    __shared__ int l_base[NSPEC];

    int bx = blockIdx.x;
    int t = threadIdx.x;

    // ================= phase 1: bucket + out-zero + weight pack =================
    if (bx < BUCKET_BLOCKS) {
        if (bx == 0) {   // zero out[1024] (256 float4)
            float4 z = {0.f, 0.f, 0.f, 0.f};
            ((float4*)out)[t] = z;
            ((float4*)out)[t + 128] = z;
        }
        if (t < NSPEC) l_cnt[t] = 0;
        __syncthreads();
        int i = bx * 128 + t;
        int s = species[i];
        int lpos = atomicAdd(&l_cnt[s], 1);
        __syncthreads();
        if (t < NSPEC) l_base[t] = atomicAdd(&g_cnt[t], l_cnt[t]);
        __syncthreads();
        bucket[s * NATOMS + l_base[s] + lpos] = (u16)i;
    } else {
        for (int tile = bx - BUCKET_BLOCKS; tile < NTILE_TOTAL; tile += GRID - BUCKET_BLOCKS) {
            if (tile < 112) {
                pack_tile<12, 16>(W1, w1p, tile / 16, tile % 16, smem);
            } else if (tile < 196) {
                int u = tile - 112;
                pack_tile<8, 12>(W2, w2p, u / 12, u % 12, smem);
            } else {
                int u = tile - 196;
                pack_tile<6, 10>(W3, w3p, u / 10, u % 10, smem);
            }
        }
    }

    __threadfence();            // device-scope release of bucket/g_cnt/w*p/out
    cg::this_grid().sync();     // cooperative grid barrier

    // ================= phase 2: persistent MLP loop (R5 body) =================
    int s = bx & 7;
    if (s >= NSPEC) return;
    int cnt = g_cnt[s];
    int w = t >> 6, lane = t & 63;
    int nl = lane & 15, kg4 = lane >> 4;
    u16* buf = smem + (size_t)w * (32 * BUFST);   // wave-private half

    for (int j = 0; j < 8; ++j) {
        int chunk = (bx >> 3) + j * 64;           // covers [0, 512)... see below
        // GRID=512: bx>>3 in [0,64); 8 iters of +64 cover chunk in [0,512).
        // Need chunk in [0, 768): species max cnt <= NATOMS, but actual per-species
        // cnt ~7000 -> ceil(7000/64)=110 chunks. 512 chunks * 64 atoms = 32768 >
        // any realistic cnt; guard below also handles the general bound.
        int base = chunk * 64 + w * 32;
        if (base >= cnt) continue;

        // ---- layer 1: 384 -> 256. A from global fp32 aev ----
        short8 af0[12], af1[12];
        {
            int i0 = base + nl;       if (i0 >= cnt) i0 = cnt - 1;
            int i1 = base + 16 + nl;  if (i1 >= cnt) i1 = cnt - 1;
            int a0 = (int)bucket[s * NATOMS + i0];
            int a1 = (int)bucket[s * NATOMS + i1];
            const float* ar0 = aev + (size_t)a0 * FDIM;
            const float* ar1 = aev + (size_t)a1 * FDIM;
#pragma unroll
            for (int kg = 0; kg < 12; ++kg) {
                const float4* p0 = (const float4*)(ar0 + kg * 32 + kg4 * 8);
                const float4* p1 = (const float4*)(ar1 + kg * 32 + kg4 * 8);
                float4 a = p0[0], b = p0[1];
                float4 c = p1[0], d = p1[1];
                U8 x, y;
                x.u[0] = bfr(a.x); x.u[1] = bfr(a.y); x.u[2] = bfr(a.z); x.u[3] = bfr(a.w);
                x.u[4] = bfr(b.x); x.u[5] = bfr(b.y); x.u[6] = bfr(b.z); x.u[7] = bfr(b.w);
                y.u[0] = bfr(c.x); y.u[1] = bfr(c.y); y.u[2] = bfr(c.z); y.u[3] = bfr(c.w);
                y.u[4] = bfr(d.x); y.u[5] = bfr(d.y); y.u[6] = bfr(d.z); y.u[7] = bfr(d.w);
                af0[kg] = x.v;
                af1[kg] = y.v;
            }
        }
        run_layer<12, 16, 2>(af0, af1, w1p + (size_t)s * W1_ELEMS_PER_S, b1 + s * 256, buf, lane);

        // ---- layer 2: 256 -> 192 ----
        short8 c0[8], c1[8];
        load_a_lds<8>(buf, c0, c1, lane);
        run_layer<8, 12, 3>(c0, c1, w2p + (size_t)s * W2_ELEMS_PER_S, b2 + s * 192, buf, lane);

        // ---- layer 3: 192 -> 160 ----
        short8 d0[6], d1[6];
        load_a_lds<6>(buf, d0, d1, lane);
        run_layer<6, 10, 3>(d0, d1, w3p + (size_t)s * W3_ELEMS_PER_S, b3 + s * 160, buf, lane);

        // ---- layer 4: 160 -> 1 (fp32 VALU) + molecule scatter-add ----
        {
            int m = lane >> 1, q = lane & 1;
            const u16* h = buf + (size_t)m * BUFST + q * 80;
            const float* w4s = W4 + s * 160 + q * 80;
            float p = 0.f;
#pragma unroll
            for (int c = 0; c < 10; ++c) {
                short8 hv = *reinterpret_cast<const short8*>(h + c * 8);
                const float4* wp4 = (const float4*)(w4s + c * 8);
                float4 wa = wp4[0], wb = wp4[1];
                p += bf2f(hv[0]) * wa.x + bf2f(hv[1]) * wa.y + bf2f(hv[2]) * wa.z + bf2f(hv[3]) * wa.w;
                p += bf2f(hv[4]) * wb.x + bf2f(hv[5]) * wb.y + bf2f(hv[6]) * wb.z + bf2f(hv[7]) * wb.w;
            }
            p += __shfl_down(p, 1, 2);
            int idx = base + m;
            if (q == 0 && idx < cnt) {
                int atom = (int)bucket[s * NATOMS + idx];
                atomicAdd(&out[atom / APM], p + b4[s]);
            }
        }
    }
}

extern "C" void kernel_launch(void* const* d_in, const int* in_sizes, int n_in,
                              void* d_out, int out_size, void* d_ws, size_t ws_size,
                              hipStream_t stream) {
    const int* species = (const int*)d_in[0];
    const float* aev = (const float*)d_in[1];
    const float* W1 = (const float*)d_in[2];
    const float* b1 = (const float*)d_in[3];
    const float* W2 = (const float*)d_in[4];
    const float* b2 = (const float*)d_in[5];
    const float* W3 = (const float*)d_in[6];
    const float* b3 = (const float*)d_in[7];
    const float* W4 = (const float*)d_in[8];
    const float* b4 = (const float*)d_in[9];
    float* out = (float*)d_out;

    unsigned char* wsb = (unsigned char*)d_ws;
    int* g_cnt = (int*)wsb;
    u16* w1p = (u16*)(wsb + WS_W1_OFF);
    u16* w2p = (u16*)(wsb + WS_W2_OFF);
    u16* w3p = (u16*)(wsb + WS_W3_OFF);
    u16* bucket = (u16*)(wsb + WS_BKT_OFF);

    hipMemsetAsync(g_cnt, 0, 8 * sizeof(int), stream);

    void* args[] = {
        (void*)&species, (void*)&aev,
        (void*)&W1, (void*)&W2, (void*)&W3,
        (void*)&b1, (void*)&b2, (void*)&b3,
        (void*)&W4, (void*)&b4,
        (void*)&g_cnt, (void*)&bucket,
        (void*)&w1p, (void*)&w2p, (void*)&w3p,
        (void*)&out,
    };
    hipLaunchCooperativeKernel((void*)fused_kernel, dim3(GRID), dim3(128),
                               args, 0, stream);
}

// Round 7
// 208.988 us; speedup vs baseline: 2.9160x; 2.9160x over previous
//
#include <hip/hip_runtime.h>
#include <math.h>

#define NSPEC 7
#define NMOL 1024
#define APM 48
#define NATOMS (NMOL * APM)   // 49152
#define FDIM 384

typedef unsigned short u16;
typedef unsigned int u32;
typedef __attribute__((ext_vector_type(8))) short short8;
typedef __attribute__((ext_vector_type(4))) float floatx4;

// Packed-weight geometry: [s][tile][kg][lane(64)][8] bf16 — tile-contiguous
// (tile block = KGS KB), which is what the global->LDS staging relies on.
#define W1_ELEMS_PER_S (16 * 12 * 64 * 8)   // 98304
#define W2_ELEMS_PER_S (12 * 8 * 64 * 8)    // 49152
#define W3_ELEMS_PER_S (10 * 6 * 64 * 8)    // 30720

#define BKT_BLOCKS 12                        // 12 x 1024 thr x 4 atoms: atomic chain depth 12
#define PACK_TILES 266                       // 112 W1 + 84 W2 + 70 W3
#define PREP_BLOCKS (BKT_BLOCKS + PACK_TILES)

// ws layout (bytes): g_cnt[8] @0, w1p @32, w2p, w3p, bucket u16[7*NATOMS]. ~3.2 MB.
#define WS_W1_OFF 32
#define WS_W2_OFF (WS_W1_OFF + 1376256)
#define WS_W3_OFF (WS_W2_OFF + 688128)
#define WS_BKT_OFF (WS_W3_OFF + 430080)

#define BUFST 264   // activation row stride in u16 (16B-aligned)
#define BSTW 6144   // one B staging buffer: 12 KB in u16 units

__device__ __forceinline__ float celu01(float x) {
    float e = fmaf(0.1f, __expf(x * 10.0f), -0.1f);   // validated R4-R6
    return x > 0.0f ? x : e;
}

__device__ __forceinline__ u16 bfr(float f) {  // fp32 -> bf16 RNE
    u32 u = __float_as_uint(f);
    u += 0x7fffu + ((u >> 16) & 1u);
    return (u16)(u >> 16);
}

__device__ __forceinline__ float bf2f(short s) {
    return __uint_as_float(((u32)(u16)s) << 16);
}

union U8 { short8 v; u16 u[8]; };

// ---------------- prep (1024 threads): bucket + out-zero + pack ----------------
template <int KGS, int NTILES>
__device__ __forceinline__ void pack_tile(const float* __restrict__ W,
                                          u16* __restrict__ dst,
                                          int s, int t2, u16* lds) {
    const int K = KGS * 32;
    const int K4 = K / 4;
    int t = threadIdx.x;
    const float* wbase = W + (size_t)(s * NTILES + t2) * 16 * K;
    for (int i = t; i < 16 * K4; i += 1024) {
        int r = i / K4, c = i - r * K4;
        float4 v = ((const float4*)(wbase + (size_t)r * K))[c];
        u16* d = lds + r * K + c * 4;
        d[0] = bfr(v.x); d[1] = bfr(v.y); d[2] = bfr(v.z); d[3] = bfr(v.w);
    }
    __syncthreads();
    int wv = t >> 6, lane = t & 63;
    int n = lane & 15, ks = lane >> 4;
    for (int kg = wv; kg < KGS; kg += 16) {
        short8 v = *reinterpret_cast<const short8*>(lds + n * K + kg * 32 + ks * 8);
        *reinterpret_cast<short8*>(
            dst + (((size_t)(s * NTILES + t2) * KGS + kg) * 64 + lane) * 8) = v;
    }
}

__global__ __launch_bounds__(1024) void prep_kernel(
    const int* __restrict__ species,
    int* __restrict__ g_cnt, u16* __restrict__ bucket,
    const float* __restrict__ W1, const float* __restrict__ W2,
    const float* __restrict__ W3,
    u16* __restrict__ w1p, u16* __restrict__ w2p, u16* __restrict__ w3p,
    float* __restrict__ out) {
    __shared__ __align__(16) u16 lds[16 * 384];
    __shared__ int l_cnt[NSPEC];
    __shared__ int l_base[NSPEC];
    int t = threadIdx.x;
    int bx = blockIdx.x;
    if (bx < BKT_BLOCKS) {
        if (bx == 0) out[t] = 0.0f;          // zero out[1024]; mlp runs after us
        if (t < NSPEC) l_cnt[t] = 0;
        __syncthreads();
        int sp[4], lp[4];
#pragma unroll
        for (int j = 0; j < 4; ++j) {
            int i = bx * 4096 + j * 1024 + t;
            sp[j] = species[i];
            lp[j] = atomicAdd(&l_cnt[sp[j]], 1);
        }
        __syncthreads();
        if (t < NSPEC) l_base[t] = atomicAdd(&g_cnt[t], l_cnt[t]);
        __syncthreads();
#pragma unroll
        for (int j = 0; j < 4; ++j) {
            int i = bx * 4096 + j * 1024 + t;
            bucket[sp[j] * NATOMS + l_base[sp[j]] + lp[j]] = (u16)i;
        }
    } else {
        int tile = bx - BKT_BLOCKS;
        if (tile < 112) {
            pack_tile<12, 16>(W1, w1p, tile / 16, tile % 16, lds);
        } else if (tile < 196) {
            int u = tile - 112;
            pack_tile<8, 12>(W2, w2p, u / 12, u % 12, lds);
        } else {
            int u = tile - 196;
            pack_tile<6, 10>(W3, w3p, u / 10, u % 10, lds);
        }
    }
}

// ---------------- global->LDS B staging (16 B/lane, wave-uniform LDS base) ----------------
template <int KGS>
__device__ __forceinline__ void stage(const u16* __restrict__ gsrc,
                                      u16* __restrict__ ldst, int tid) {
    int w = tid >> 6, lane = tid & 63;
#pragma unroll
    for (int r = 0; r < KGS / 2; ++r) {
        int off = r * 1024 + w * 512;        // u16 units; per-wave contiguous 1 KB
        __builtin_amdgcn_global_load_lds(
            (const __attribute__((address_space(1))) unsigned int*)(gsrc + off + lane * 8),
            (__attribute__((address_space(3))) unsigned int*)(ldst + off),
            16, 0, 0);
    }
}

// ---------------- MFMA layer: 2 waves share LDS-staged B, dbuf'd one tile ahead ----------------
// Per iteration: barrier (drains stage(t), fences buf[(t-1)&1] readers) ->
// issue stage(t+1) -> ds_read tile t frags -> MFMA -> epilogue. All NT even,
// so the last tile reads buf1 and the next layer's stage(0) into buf0 is race-free.
template <int KGS, int NT>
__device__ __forceinline__ void run_layer(const short8* af0, const short8* af1,
                                          const u16* __restrict__ wsp,
                                          const float* __restrict__ bias,
                                          u16* __restrict__ outbuf,
                                          u16* __restrict__ bst,   // 2*BSTW u16
                                          int tid, int lane) {
    const int nl = lane & 15, kg4 = lane >> 4;
    stage<KGS>(wsp, bst, tid);               // tile 0 -> buffer 0
#pragma unroll
    for (int t = 0; t < NT; ++t) {
        __syncthreads();
        if (t + 1 < NT)
            stage<KGS>(wsp + (size_t)(t + 1) * (KGS * 512), bst + ((t + 1) & 1) * BSTW, tid);
        const u16* bb = bst + (t & 1) * BSTW + lane * 8;
        short8 bf[KGS];
#pragma unroll
        for (int kg = 0; kg < KGS; ++kg)
            bf[kg] = *reinterpret_cast<const short8*>(bb + kg * 512);
        floatx4 acc0 = {0.f, 0.f, 0.f, 0.f};
        floatx4 acc1 = {0.f, 0.f, 0.f, 0.f};
#pragma unroll
        for (int kg = 0; kg < KGS; ++kg) {
            acc0 = __builtin_amdgcn_mfma_f32_16x16x32_bf16(af0[kg], bf[kg], acc0, 0, 0, 0);
            acc1 = __builtin_amdgcn_mfma_f32_16x16x32_bf16(af1[kg], bf[kg], acc1, 0, 0, 0);
        }
        float bn = bias[t * 16 + nl];
#pragma unroll
        for (int r = 0; r < 4; ++r) {
            outbuf[(kg4 * 4 + r) * BUFST + t * 16 + nl] = bfr(celu01(acc0[r] + bn));
            outbuf[(16 + kg4 * 4 + r) * BUFST + t * 16 + nl] = bfr(celu01(acc1[r] + bn));
        }
    }
}

template <int KGS>
__device__ __forceinline__ void load_a_lds(const u16* __restrict__ buf,
                                           short8* af0, short8* af1, int lane) {
    int nl = lane & 15, kg4 = lane >> 4;
#pragma unroll
    for (int kg = 0; kg < KGS; ++kg) {
        af0[kg] = *reinterpret_cast<const short8*>(buf + (size_t)nl * BUFST + kg * 32 + kg4 * 8);
        af1[kg] = *reinterpret_cast<const short8*>(buf + (size_t)(16 + nl) * BUFST + kg * 32 + kg4 * 8);
    }
}

__global__ __launch_bounds__(128, 2) void mlp_kernel(
    const float* __restrict__ aev,
    const u16* __restrict__ w1p, const u16* __restrict__ w2p, const u16* __restrict__ w3p,
    const float* __restrict__ b1, const float* __restrict__ b2, const float* __restrict__ b3,
    const float* __restrict__ W4, const float* __restrict__ b4,
    const int* __restrict__ g_cnt, const u16* __restrict__ bucket,
    float* __restrict__ out) {
    int bx = blockIdx.x;
    int s = bx & 7;                      // XCD pinning (perf heuristic only)
    if (s >= NSPEC) return;
    int chunk = bx >> 3;
    int cnt = g_cnt[s];
    if (chunk * 64 >= cnt) return;       // BLOCK-uniform exit (barriers inside!)

    __shared__ __align__(16) u16 act[2][32 * BUFST];   // 33792 B: per-wave activations
    __shared__ __align__(16) u16 bst[2][BSTW];         // 24576 B: shared B double-buffer

    int tid = threadIdx.x;
    int w = tid >> 6, lane = tid & 63;
    int nl = lane & 15, kg4 = lane >> 4;
    int base = chunk * 64 + w * 32;      // wave 1 may be fully padded; stores suppressed
    u16* buf = &act[w][0];

    // ---- layer 1 A: gather 32 fp32 aev rows -> bf16 frags (issued before staging) ----
    short8 af0[12], af1[12];
    {
        int i0 = base + nl;       if (i0 >= cnt) i0 = cnt - 1;
        int i1 = base + 16 + nl;  if (i1 >= cnt) i1 = cnt - 1;
        int a0 = (int)bucket[s * NATOMS + i0];
        int a1 = (int)bucket[s * NATOMS + i1];
        const float* ar0 = aev + (size_t)a0 * FDIM;
        const float* ar1 = aev + (size_t)a1 * FDIM;
#pragma unroll
        for (int kg = 0; kg < 12; ++kg) {
            const float4* p0 = (const float4*)(ar0 + kg * 32 + kg4 * 8);
            const float4* p1 = (const float4*)(ar1 + kg * 32 + kg4 * 8);
            float4 a = p0[0], b = p0[1];
            float4 c = p1[0], d = p1[1];
            U8 x, y;
            x.u[0] = bfr(a.x); x.u[1] = bfr(a.y); x.u[2] = bfr(a.z); x.u[3] = bfr(a.w);
            x.u[4] = bfr(b.x); x.u[5] = bfr(b.y); x.u[6] = bfr(b.z); x.u[7] = bfr(b.w);
            y.u[0] = bfr(c.x); y.u[1] = bfr(c.y); y.u[2] = bfr(c.z); y.u[3] = bfr(c.w);
            y.u[4] = bfr(d.x); y.u[5] = bfr(d.y); y.u[6] = bfr(d.z); y.u[7] = bfr(d.w);
            af0[kg] = x.v;
            af1[kg] = y.v;
        }
    }

    // ---- layer 1: 384 -> 256 ----
    run_layer<12, 16>(af0, af1, w1p + (size_t)s * W1_ELEMS_PER_S, b1 + s * 256,
                      buf, &bst[0][0], tid, lane);

    // ---- layer 2: 256 -> 192 ----
    short8 c0[8], c1[8];
    load_a_lds<8>(buf, c0, c1, lane);
    run_layer<8, 12>(c0, c1, w2p + (size_t)s * W2_ELEMS_PER_S, b2 + s * 192,
                     buf, &bst[0][0], tid, lane);

    // ---- layer 3: 192 -> 160 ----
    short8 d0[6], d1[6];
    load_a_lds<6>(buf, d0, d1, lane);
    run_layer<6, 10>(d0, d1, w3p + (size_t)s * W3_ELEMS_PER_S, b3 + s * 160,
                     buf, &bst[0][0], tid, lane);

    // ---- layer 4: 160 -> 1 (fp32 VALU) + molecule scatter-add ----
    {
        int m = lane >> 1, q = lane & 1;
        const u16* h = buf + (size_t)m * BUFST + q * 80;
        const float* w4s = W4 + s * 160 + q * 80;
        float p = 0.f;
#pragma unroll
        for (int c = 0; c < 10; ++c) {
            short8 hv = *reinterpret_cast<const short8*>(h + c * 8);
            const float4* wp4 = (const float4*)(w4s + c * 8);
            float4 wa = wp4[0], wb = wp4[1];
            p += bf2f(hv[0]) * wa.x + bf2f(hv[1]) * wa.y + bf2f(hv[2]) * wa.z + bf2f(hv[3]) * wa.w;
            p += bf2f(hv[4]) * wb.x + bf2f(hv[5]) * wb.y + bf2f(hv[6]) * wb.z + bf2f(hv[7]) * wb.w;
        }
        p += __shfl_down(p, 1, 2);
        int idx = base + m;
        if (q == 0 && idx < cnt) {
            int atom = (int)bucket[s * NATOMS + idx];
            atomicAdd(&out[atom / APM], p + b4[s]);
        }
    }
}

extern "C" void kernel_launch(void* const* d_in, const int* in_sizes, int n_in,
                              void* d_out, int out_size, void* d_ws, size_t ws_size,
                              hipStream_t stream) {
    const int* species = (const int*)d_in[0];
    const float* aev = (const float*)d_in[1];
    const float* W1 = (const float*)d_in[2];
    const float* b1 = (const float*)d_in[3];
    const float* W2 = (const float*)d_in[4];
    const float* b2 = (const float*)d_in[5];
    const float* W3 = (const float*)d_in[6];
    const float* b3 = (const float*)d_in[7];
    const float* W4 = (const float*)d_in[8];
    const float* b4 = (const float*)d_in[9];
    float* out = (float*)d_out;

    unsigned char* wsb = (unsigned char*)d_ws;
    int* g_cnt = (int*)wsb;
    u16* w1p = (u16*)(wsb + WS_W1_OFF);
    u16* w2p = (u16*)(wsb + WS_W2_OFF);
    u16* w3p = (u16*)(wsb + WS_W3_OFF);
    u16* bucket = (u16*)(wsb + WS_BKT_OFF);

    hipMemsetAsync(g_cnt, 0, 8 * sizeof(int), stream);

    prep_kernel<<<PREP_BLOCKS, 1024, 0, stream>>>(
        species, g_cnt, bucket, W1, W2, W3, w1p, w2p, w3p, out);

    mlp_kernel<<<8 * (NATOMS / 64), 128, 0, stream>>>(
        aev, w1p, w2p, w3p, b1, b2, b3, W4, b4, g_cnt, bucket, out);
}